// Round 1
// baseline (57.328 us; speedup 1.0000x reference)
//
#include <hip/hip_runtime.h>
#include <hip/hip_bf16.h>

#define B_  4
#define C_  640
#define H_  64
#define W_  64
#define G_  16          // channel groups (one wave each)
#define CPG 40          // channels per group: G_*CPG == C_
#define NT  1024

__global__ __launch_bounds__(NT) void nca_fused(
    const float* __restrict__ Ft,
    const float* __restrict__ Fwp,
    const float* __restrict__ mask,
    const float* __restrict__ cw,
    const float* __restrict__ cb,
    float* __restrict__ out)
{
    __shared__ float lds_cw[2 * C_];            // 5 KB   conv weights
    __shared__ float lds_sim[G_][W_][9];        // 36 KB  sim partials
    __shared__ float lds_sm[W_][9];             // 2.25 KB masked sim
    __shared__ float lds_attn[W_][9];           // 2.25 KB attn weights
    __shared__ float lds_red[G_][W_];           // 4 KB   lambda-dot partials
    __shared__ float lds_lamT[W_];              // Ft part of lambda dot
    __shared__ float lds_lam[W_];               // final lambda
    __shared__ __hip_bfloat16 lds_fw[C_][W_];   // 80 KB  weighted Fwarp

    const int t = threadIdx.x;
    const int w = t & 63;       // lane == w within each wave
    const int g = t >> 6;       // channel group == wave id
    const int h = blockIdx.x;
    const int b = blockIdx.y;

    // stage conv weights
    for (int i = t; i < 2 * C_; i += NT) lds_cw[i] = cw[i];
    __syncthreads();

    const int hm = (h > 0) ? (h - 1) : 0;
    const int hp = (h < H_ - 1) ? (h + 1) : (H_ - 1);
    const size_t cs = (size_t)H_ * W_;          // channel stride (elements)
    const int c0 = g * CPG;

    const float* ftp = Ft  + ((size_t)(b * C_ + c0) * H_ + h ) * W_ + w;
    const float* f0p = Fwp + ((size_t)(b * C_ + c0) * H_ + hm) * W_ + w;
    const float* f1p = Fwp + ((size_t)(b * C_ + c0) * H_ + h ) * W_ + w;
    const float* f2p = Fwp + ((size_t)(b * C_ + c0) * H_ + hp) * W_ + w;

    // ---------------- Pass A: sim partials (displaced accumulation) --------
    // sC[r]: ft[w]   * fw[r][w]   -> pixel w,   dj =  0
    // sA[r]: ft[w+1] * fw[r][w]   -> pixel w+1, dj = -1 (realigned later)
    // sB[r]: ft[w-1] * fw[r][w]   -> pixel w-1, dj = +1 (realigned later)
    float sC0=0.f, sC1=0.f, sC2=0.f;
    float sA0=0.f, sA1=0.f, sA2=0.f;
    float sB0=0.f, sB1=0.f, sB2=0.f;
    float lamT = 0.f;
    const int lnL = (w - 1) & 63;
    const int lnR = (w + 1) & 63;

    #pragma unroll 8
    for (int k = 0; k < CPG; ++k) {
        float ft = ftp[k * cs];
        float f0 = f0p[k * cs];
        float f1 = f1p[k * cs];
        float f2 = f2p[k * cs];
        float ftL = __shfl(ft, lnL, 64);   // ft[w-1] (lane 0 wraps: discarded)
        float ftR = __shfl(ft, lnR, 64);   // ft[w+1] (lane 63 wraps: discarded)
        sC0 = fmaf(ft , f0, sC0); sC1 = fmaf(ft , f1, sC1); sC2 = fmaf(ft , f2, sC2);
        sA0 = fmaf(ftR, f0, sA0); sA1 = fmaf(ftR, f1, sA1); sA2 = fmaf(ftR, f2, sA2);
        sB0 = fmaf(ftL, f0, sB0); sB1 = fmaf(ftL, f1, sB1); sB2 = fmaf(ftL, f2, sB2);
        lamT = fmaf(lds_cw[C_ + c0 + k], ft, lamT);   // Ft half of lambda dot
    }

    // realign displaced accumulators to the owning pixel
    float simn[9];
    simn[1] = sC0; simn[4] = sC1; simn[7] = sC2;
    simn[0] = __shfl(sA0, lnL, 64);
    simn[3] = __shfl(sA1, lnL, 64);
    simn[6] = __shfl(sA2, lnL, 64);
    simn[2] = __shfl(sB0, lnR, 64);
    simn[5] = __shfl(sB1, lnR, 64);
    simn[8] = __shfl(sB2, lnR, 64);
    // replicate-pad columns: clamped neighbor == center product
    if (w == 0)      { simn[0] = sC0; simn[3] = sC1; simn[6] = sC2; }
    if (w == W_ - 1) { simn[2] = sC0; simn[5] = sC1; simn[8] = sC2; }

    #pragma unroll
    for (int n = 0; n < 9; ++n) lds_sim[g][w][n] = simn[n];
    lds_red[g][w] = lamT;
    __syncthreads();

    // ---------------- reduce across groups + mask --------------------------
    if (t < W_ * 9) {
        const int ww = t / 9, n = t % 9;
        float s = 0.f;
        #pragma unroll
        for (int gg = 0; gg < G_; ++gg) s += lds_sim[gg][ww][n];
        s *= 0.0395284707521f;              // 1/sqrt(640)
        const int r = n / 3, j = n % 3;
        const int row = (r == 0) ? hm : ((r == 1) ? h : hp);
        int col = ww + j - 1;
        col = col < 0 ? 0 : (col > W_ - 1 ? W_ - 1 : col);
        const float mv = mask[((size_t)b * H_ + row) * W_ + col];
        if (mv == 1.0f) s = -1e9f;          // occluded neighbor
        lds_sm[ww][n] = s;
    }
    __syncthreads();

    // ---------------- softmax per pixel + lamT reduce ----------------------
    if (t < W_) {
        float v[9];
        float mx = -3e38f;
        bool valid = false;
        #pragma unroll
        for (int n = 0; n < 9; ++n) {
            v[n] = lds_sm[t][n];
            if (v[n] > -5e8f) valid = true;     // real sims are |.| < 1e3
            mx = fmaxf(mx, v[n]);
        }
        float lt = 0.f;
        #pragma unroll
        for (int gg = 0; gg < G_; ++gg) lt += lds_red[gg][t];
        lds_lamT[t] = lt;
        if (!valid) {
            #pragma unroll
            for (int n = 0; n < 9; ++n) lds_attn[t][n] = 0.f;
        } else {
            float e[9], sum = 0.f;
            #pragma unroll
            for (int n = 0; n < 9; ++n) { e[n] = expf(v[n] - mx); sum += e[n]; }
            const float inv = 1.f / sum;
            #pragma unroll
            for (int n = 0; n < 9; ++n) lds_attn[t][n] = e[n] * inv;
        }
    }
    __syncthreads();

    // ---------------- Pass B: Fw = attn-weighted neighborhood --------------
    float a[9];
    #pragma unroll
    for (int n = 0; n < 9; ++n) a[n] = lds_attn[w][n];
    const int sL = (w == 0)      ? 0      : (w - 1);   // replicate clamp
    const int sR = (w == W_ - 1) ? W_ - 1 : (w + 1);
    float lamF = 0.f;

    #pragma unroll 4
    for (int k = 0; k < CPG; ++k) {
        float f0 = f0p[k * cs];
        float f1 = f1p[k * cs];
        float f2 = f2p[k * cs];
        float f0L = __shfl(f0, sL, 64), f0R = __shfl(f0, sR, 64);
        float f1L = __shfl(f1, sL, 64), f1R = __shfl(f1, sR, 64);
        float f2L = __shfl(f2, sL, 64), f2R = __shfl(f2, sR, 64);
        float fwv = a[0]*f0L + a[1]*f0 + a[2]*f0R
                  + a[3]*f1L + a[4]*f1 + a[5]*f1R
                  + a[6]*f2L + a[7]*f2 + a[8]*f2R;
        lds_fw[c0 + k][w] = __float2bfloat16(fwv);
        lamF = fmaf(lds_cw[c0 + k], fwv, lamF);        // Fw half of lambda dot
    }
    lds_red[g][w] = lamF;
    __syncthreads();

    // ---------------- lambda = sigmoid(dot + bias) -------------------------
    if (t < W_) {
        float s = lds_lamT[t];
        #pragma unroll
        for (int gg = 0; gg < G_; ++gg) s += lds_red[gg][t];
        s += cb[0];
        lds_lam[t] = 1.f / (1.f + expf(-s));
    }
    __syncthreads();

    // ---------------- Pass C: out = lam*Ft + (1-lam)*Fw --------------------
    const float lam = lds_lam[w];
    float* outp = out + ((size_t)(b * C_ + c0) * H_ + h) * W_ + w;
    #pragma unroll 8
    for (int k = 0; k < CPG; ++k) {
        float ft  = ftp[k * cs];
        float fwv = __bfloat162float(lds_fw[c0 + k][w]);
        outp[k * cs] = lam * ft + (1.f - lam) * fwv;
    }
}

extern "C" void kernel_launch(void* const* d_in, const int* in_sizes, int n_in,
                              void* d_out, int out_size, void* d_ws, size_t ws_size,
                              hipStream_t stream) {
    const float* Ft   = (const float*)d_in[0];
    const float* Fwp  = (const float*)d_in[1];
    const float* mask = (const float*)d_in[2];
    const float* cw   = (const float*)d_in[3];
    const float* cb   = (const float*)d_in[4];
    float* out = (float*)d_out;

    dim3 grid(H_, B_);   // one block per (h, b) row: 256 blocks == 256 CUs
    dim3 block(NT);
    nca_fused<<<grid, block, 0, stream>>>(Ft, Fwp, mask, cw, cb, out);
}